// Round 7
// baseline (220.508 us; speedup 1.0000x reference)
//
#include <hip/hip_runtime.h>
#include <math.h>

// Problem constants (from reference setup_inputs)
#define BB 512
#define HH 512
#define RR 2048
#define CC 64
#define OUTD 202          // 3*64 + 2*3 + 4
// params workspace layout per batch (floats)
#define PSTRIDE 208
#define K_OFF 0
#define E_OFF 64
#define A_OFF 128
#define S_OFF 192         // 7 softmaxed shift weights
#define COMBO_OFF 199     // beta / k_n
#define G_OFF 200
#define GAMMA_OFF 201

typedef float f32x4 __attribute__((ext_vector_type(4)));

__device__ __forceinline__ float softplusf_(float x) {
    return (x > 20.f) ? x : log1pf(expf(x));
}
__device__ __forceinline__ float sigmoidf_(float x) {
    return 1.f / (1.f + expf(-x));
}

// ---------------------------------------------------------------------------
// Kernel A: z = h @ fc_w^T + fc_b, activations -> packed params in ws.
// 64 blocks x 256 threads; fc_w (414KB) stays L2-hot across 8 rows/block.
// ---------------------------------------------------------------------------
__global__ __launch_bounds__(256) void params_kernel(
    const float* __restrict__ h, const float* __restrict__ fc_w,
    const float* __restrict__ fc_b, float* __restrict__ pw)
{
    __shared__ float h_sh[8][HH];
    __shared__ float z_sh[8][204];
    const int tid = threadIdx.x;
    const int b0 = blockIdx.x * 8;

    for (int idx = tid; idx < 8 * HH; idx += 256) {
        int j = idx >> 9, i = idx & 511;
        h_sh[j][i] = h[(size_t)(b0 + j) * HH + i];
    }
    __syncthreads();

    if (tid < OUTD) {
        float acc[8];
        #pragma unroll
        for (int j = 0; j < 8; ++j) acc[j] = 0.f;
        const float4* wr4 = (const float4*)(fc_w + (size_t)tid * HH);
        for (int i4 = 0; i4 < HH / 4; ++i4) {
            float4 wv = wr4[i4];
            int i = i4 * 4;
            #pragma unroll
            for (int j = 0; j < 8; ++j) {
                acc[j] = fmaf(wv.x, h_sh[j][i + 0], acc[j]);
                acc[j] = fmaf(wv.y, h_sh[j][i + 1], acc[j]);
                acc[j] = fmaf(wv.z, h_sh[j][i + 2], acc[j]);
                acc[j] = fmaf(wv.w, h_sh[j][i + 3], acc[j]);
            }
        }
        float bias = fc_b[tid];
        #pragma unroll
        for (int j = 0; j < 8; ++j) z_sh[j][tid] = acc[j] + bias;
    }
    __syncthreads();

    for (int idx = tid; idx < 8 * OUTD; idx += 256) {
        int j = idx / OUTD;
        int t = idx - j * OUTD;
        float z = z_sh[j][t];
        float* p = pw + (size_t)(b0 + j) * PSTRIDE;
        if (t < 64)            p[K_OFF + t] = tanhf(z);
        else if (t == 65)      p[G_OFF] = sigmoidf_(z);
        else if (t == 73)      p[GAMMA_OFF] = softplusf_(z) + 1.f;
        else if (t >= 74 && t < 138) p[E_OFF + (t - 74)] = sigmoidf_(z);
        else if (t >= 138)     p[A_OFF + (t - 138)] = tanhf(z);
    }
    __syncthreads();

    if (tid < 8) {
        int j = tid;
        float* p = pw + (size_t)(b0 + j) * PSTRIDE;
        float ss = 0.f;
        for (int c = 0; c < 64; ++c) {
            float kv = tanhf(z_sh[j][c]);
            ss += kv * kv;
        }
        float kn = fmaxf(sqrtf(ss), 1e-8f);
        float beta = softplusf_(z_sh[j][64]);
        p[COMBO_OFF] = beta / kn;
        float mx = -1e30f;
        for (int q = 0; q < 7; ++q) mx = fmaxf(mx, z_sh[j][66 + q]);
        float ev[7], se = 0.f;
        for (int q = 0; q < 7; ++q) { ev[q] = expf(z_sh[j][66 + q] - mx); se += ev[q]; }
        float inv = 1.f / se;
        for (int q = 0; q < 7; ++q) p[S_OFF + q] = ev[q] * inv;
    }
}

// ---------------------------------------------------------------------------
// 16-wave (1024-thread) block reduce, fixed order -> deterministic
// ---------------------------------------------------------------------------
__device__ __forceinline__ float block_reduce_sum16(float v, float* red) {
    #pragma unroll
    for (int m = 1; m < 64; m <<= 1) v += __shfl_xor(v, m, 64);
    int wid = threadIdx.x >> 6;
    if ((threadIdx.x & 63) == 0) red[wid] = v;
    __syncthreads();
    if (threadIdx.x < 16) {
        float x = red[threadIdx.x];
        #pragma unroll
        for (int m = 1; m < 16; m <<= 1) x += __shfl_xor(x, m, 64);
        if (threadIdx.x == 0) red[0] = x;
    }
    __syncthreads();
    float r = red[0];
    __syncthreads();
    return r;
}

// ---------------------------------------------------------------------------
// Fused kernel: one block per batch, 1024 threads, 8 lanes per row (32B/lane).
// phase 0: stream memory[b] once; ev=exp(combo*cos) -> LDS + running sum
//          (max-free softmax is exact: |arg| <= beta, small)
// phase A: gate with prev_w -> 7-tap circular conv -> pow -> sum (all LDS,
//          single pass each, 2 reduces total)
// phase B: re-read memory[b] (L2/L3-hot: R1 measured FETCH=264MB => absorbed)
//          normalize w on the fly, write out_w + NT-store new_mem.
// ---------------------------------------------------------------------------
__global__ __launch_bounds__(1024) void fused_kernel(
    const float* __restrict__ memory, const float* __restrict__ prev_w,
    const float* __restrict__ pw, float* __restrict__ out_w,
    float* __restrict__ out_mem)
{
    __shared__ float evs[RR];      // ev  -> w_p
    __shared__ float wg[RR];       // gated weights -> final w
    __shared__ float red[16];

    const int b = blockIdx.x;
    const int tid = threadIdx.x;
    const int lane8 = tid & 7;
    const int rgrp = tid >> 3;             // 0..127
    const float* p = pw + (size_t)b * PSTRIDE;

    const f32x4 ka = *(const f32x4*)(p + K_OFF + lane8 * 8);
    const f32x4 kb = *(const f32x4*)(p + K_OFF + lane8 * 8 + 4);
    const float combo = p[COMBO_OFF];
    const float* memb = memory + (size_t)b * RR * CC;

    // ---- phase 0: stream + cosine + exp ----
    float lsum = 0.f;
    #pragma unroll 8
    for (int i = 0; i < 16; ++i) {
        int r = i * 128 + rgrp;
        const f32x4* mp = (const f32x4*)(memb + (size_t)r * CC + lane8 * 8);
        f32x4 ma = mp[0];
        f32x4 mb = mp[1];
        float num = ma.x * ka.x + ma.y * ka.y + ma.z * ka.z + ma.w * ka.w
                  + mb.x * kb.x + mb.y * kb.y + mb.z * kb.z + mb.w * kb.w;
        float ssq = ma.x * ma.x + ma.y * ma.y + ma.z * ma.z + ma.w * ma.w
                  + mb.x * mb.x + mb.y * mb.y + mb.z * mb.z + mb.w * mb.w;
        #pragma unroll
        for (int m = 1; m < 8; m <<= 1) {
            num += __shfl_xor(num, m, 64);
            ssq += __shfl_xor(ssq, m, 64);
        }
        if (lane8 == 0) {
            float mn = fmaxf(sqrtf(ssq), 1e-8f);
            float ev = __expf(combo * num / mn);
            evs[r] = ev;
            lsum += ev;
        }
    }
    const float se = block_reduce_sum16(lsum, red);   // barrier covers evs

    // ---- phase A ----
    const float g = p[G_OFF];
    const float gamma = p[GAMMA_OFF];
    const float s0 = p[S_OFF + 0], s1 = p[S_OFF + 1], s2 = p[S_OFF + 2],
                s3 = p[S_OFF + 3], s4 = p[S_OFF + 4], s5 = p[S_OFF + 5],
                s6 = p[S_OFF + 6];
    const float gi = g / se, omg = 1.f - g;

    // gate: 2 rows per thread, float2 prev_w load
    {
        const int r2 = tid * 2;
        float2 pv = *(const float2*)(prev_w + (size_t)b * RR + r2);
        wg[r2]     = gi * evs[r2]     + omg * pv.x;
        wg[r2 + 1] = gi * evs[r2 + 1] + omg * pv.y;
    }
    __syncthreads();

    // conv + pow (reads wg +-3 circular, writes evs)
    float lp = 0.f;
    {
        const int r2 = tid * 2;
        #pragma unroll
        for (int q = 0; q < 2; ++q) {
            int r = r2 + q;
            float acc = s0 * wg[(r - 3) & (RR - 1)]
                      + s1 * wg[(r - 2) & (RR - 1)]
                      + s2 * wg[(r - 1) & (RR - 1)]
                      + s3 * wg[r]
                      + s4 * wg[(r + 1) & (RR - 1)]
                      + s5 * wg[(r + 2) & (RR - 1)]
                      + s6 * wg[(r + 3) & (RR - 1)];
            float v = __powf(acc, gamma);
            evs[r] = v;
            lp += v;
        }
    }
    const float ps = block_reduce_sum16(lp, red);     // barrier: conv reads done
    const float invp = 1.f / (ps + 1e-16f);

    // normalize: out_w + stash w in wg for phase B
    {
        const int r2 = tid * 2;
        float w0 = evs[r2] * invp;
        float w1 = evs[r2 + 1] * invp;
        wg[r2] = w0;
        wg[r2 + 1] = w1;
        *(float2*)(out_w + (size_t)b * RR + r2) = make_float2(w0, w1);
    }
    __syncthreads();

    // ---- phase B: memory update (re-read is cache-hot) ----
    const f32x4 ea = *(const f32x4*)(p + E_OFF + lane8 * 8);
    const f32x4 eb = *(const f32x4*)(p + E_OFF + lane8 * 8 + 4);
    const f32x4 aa = *(const f32x4*)(p + A_OFF + lane8 * 8);
    const f32x4 ab = *(const f32x4*)(p + A_OFF + lane8 * 8 + 4);
    float* omb = out_mem + (size_t)b * RR * CC;

    #pragma unroll 8
    for (int i = 0; i < 16; ++i) {
        int r = i * 128 + rgrp;
        float wv = wg[r];
        const f32x4* mp = (const f32x4*)(memb + (size_t)r * CC + lane8 * 8);
        f32x4 ma = mp[0];
        f32x4 mb = mp[1];
        f32x4 oa, ob;
        oa.x = ma.x * (1.f - wv * ea.x) + wv * aa.x;
        oa.y = ma.y * (1.f - wv * ea.y) + wv * aa.y;
        oa.z = ma.z * (1.f - wv * ea.z) + wv * aa.z;
        oa.w = ma.w * (1.f - wv * ea.w) + wv * aa.w;
        ob.x = mb.x * (1.f - wv * eb.x) + wv * ab.x;
        ob.y = mb.y * (1.f - wv * eb.y) + wv * ab.y;
        ob.z = mb.z * (1.f - wv * eb.z) + wv * ab.z;
        ob.w = mb.w * (1.f - wv * eb.w) + wv * ab.w;
        f32x4* op = (f32x4*)(omb + (size_t)r * CC + lane8 * 8);
        __builtin_nontemporal_store(oa, op);
        __builtin_nontemporal_store(ob, op + 1);
    }
}

extern "C" void kernel_launch(void* const* d_in, const int* in_sizes, int n_in,
                              void* d_out, int out_size, void* d_ws, size_t ws_size,
                              hipStream_t stream) {
    const float* h      = (const float*)d_in[0];
    const float* prev_w = (const float*)d_in[1];
    const float* memory = (const float*)d_in[2];
    const float* fc_w   = (const float*)d_in[3];
    const float* fc_b   = (const float*)d_in[4];

    float* pw      = (float*)d_ws;              // 512*208*4 = 416 KB
    float* out_w   = (float*)d_out;             // B*R
    float* out_mem = out_w + (size_t)BB * RR;   // B*R*C

    params_kernel<<<64, 256, 0, stream>>>(h, fc_w, fc_b, pw);
    fused_kernel<<<BB, 1024, 0, stream>>>(memory, prev_w, pw, out_w, out_mem);
}

// Round 8
// 220.045 us; speedup vs baseline: 1.0021x; 1.0021x over previous
//
#include <hip/hip_runtime.h>
#include <math.h>

// Problem constants (from reference setup_inputs)
#define BB 512
#define HH 512
#define RR 2048
#define CC 64
#define OUTD 202          // 3*64 + 2*3 + 4
// params workspace layout per batch (floats)
#define PSTRIDE 208
#define K_OFF 0
#define E_OFF 64
#define A_OFF 128
#define S_OFF 192         // 7 softmaxed shift weights
#define COMBO_OFF 199     // beta / k_n
#define G_OFF 200
#define GAMMA_OFF 201

typedef float f32x4 __attribute__((ext_vector_type(4)));

__device__ __forceinline__ float softplusf_(float x) {
    return (x > 20.f) ? x : log1pf(expf(x));
}
__device__ __forceinline__ float sigmoidf_(float x) {
    return 1.f / (1.f + expf(-x));
}

// ---------------------------------------------------------------------------
// Kernel A: z = h @ fc_w^T + fc_b, activations -> packed params in ws.
// ---------------------------------------------------------------------------
__global__ __launch_bounds__(256) void params_kernel(
    const float* __restrict__ h, const float* __restrict__ fc_w,
    const float* __restrict__ fc_b, float* __restrict__ pw)
{
    __shared__ float h_sh[8][HH];
    __shared__ float z_sh[8][204];
    const int tid = threadIdx.x;
    const int b0 = blockIdx.x * 8;

    for (int idx = tid; idx < 8 * HH; idx += 256) {
        int j = idx >> 9, i = idx & 511;
        h_sh[j][i] = h[(size_t)(b0 + j) * HH + i];
    }
    __syncthreads();

    if (tid < OUTD) {
        float acc[8];
        #pragma unroll
        for (int j = 0; j < 8; ++j) acc[j] = 0.f;
        const float4* wr4 = (const float4*)(fc_w + (size_t)tid * HH);
        for (int i4 = 0; i4 < HH / 4; ++i4) {
            float4 wv = wr4[i4];
            int i = i4 * 4;
            #pragma unroll
            for (int j = 0; j < 8; ++j) {
                acc[j] = fmaf(wv.x, h_sh[j][i + 0], acc[j]);
                acc[j] = fmaf(wv.y, h_sh[j][i + 1], acc[j]);
                acc[j] = fmaf(wv.z, h_sh[j][i + 2], acc[j]);
                acc[j] = fmaf(wv.w, h_sh[j][i + 3], acc[j]);
            }
        }
        float bias = fc_b[tid];
        #pragma unroll
        for (int j = 0; j < 8; ++j) z_sh[j][tid] = acc[j] + bias;
    }
    __syncthreads();

    for (int idx = tid; idx < 8 * OUTD; idx += 256) {
        int j = idx / OUTD;
        int t = idx - j * OUTD;
        float z = z_sh[j][t];
        float* p = pw + (size_t)(b0 + j) * PSTRIDE;
        if (t < 64)            p[K_OFF + t] = tanhf(z);
        else if (t == 65)      p[G_OFF] = sigmoidf_(z);
        else if (t == 73)      p[GAMMA_OFF] = softplusf_(z) + 1.f;
        else if (t >= 74 && t < 138) p[E_OFF + (t - 74)] = sigmoidf_(z);
        else if (t >= 138)     p[A_OFF + (t - 138)] = tanhf(z);
    }
    __syncthreads();

    if (tid < 8) {
        int j = tid;
        float* p = pw + (size_t)(b0 + j) * PSTRIDE;
        float ss = 0.f;
        for (int c = 0; c < 64; ++c) {
            float kv = tanhf(z_sh[j][c]);
            ss += kv * kv;
        }
        float kn = fmaxf(sqrtf(ss), 1e-8f);
        float beta = softplusf_(z_sh[j][64]);
        p[COMBO_OFF] = beta / kn;
        float mx = -1e30f;
        for (int q = 0; q < 7; ++q) mx = fmaxf(mx, z_sh[j][66 + q]);
        float ev[7], se = 0.f;
        for (int q = 0; q < 7; ++q) { ev[q] = expf(z_sh[j][66 + q] - mx); se += ev[q]; }
        float inv = 1.f / se;
        for (int q = 0; q < 7; ++q) p[S_OFF + q] = ev[q] * inv;
    }
}

// ---------------------------------------------------------------------------
// 16-wave (1024-thread) block reduce, fixed order -> deterministic
// ---------------------------------------------------------------------------
__device__ __forceinline__ float block_reduce_sum16(float v, float* red) {
    #pragma unroll
    for (int m = 1; m < 64; m <<= 1) v += __shfl_xor(v, m, 64);
    int wid = threadIdx.x >> 6;
    if ((threadIdx.x & 63) == 0) red[wid] = v;
    __syncthreads();
    if (threadIdx.x < 16) {
        float x = red[threadIdx.x];
        #pragma unroll
        for (int m = 1; m < 16; m <<= 1) x += __shfl_xor(x, m, 64);
        if (threadIdx.x == 0) red[0] = x;
    }
    __syncthreads();
    float r = red[0];
    __syncthreads();
    return r;
}

// ---------------------------------------------------------------------------
// Fused kernel: one block per batch, 1024 threads, 8 lanes per row.
// KEY CHANGE vs R7: 4-row macro-iterations in both streaming phases — 8
// independent dwordx4 loads issued before any use (128 B/thread in flight,
// 4x deeper memory pipeline; VGPR_Count 36 -> ~100 is intended).
// __launch_bounds__(1024,4): 1 block/CU, frees VGPR budget to 128.
// Plain stores (NT stores measured +50% WRITE_SIZE in R7: 402 vs 267 MB).
// ---------------------------------------------------------------------------
__global__ __launch_bounds__(1024, 4) void fused_kernel(
    const float* __restrict__ memory, const float* __restrict__ prev_w,
    const float* __restrict__ pw, float* __restrict__ out_w,
    float* __restrict__ out_mem)
{
    __shared__ float evs[RR];      // ev  -> w_p
    __shared__ float wg[RR];       // gated weights -> final w
    __shared__ float red[16];

    const int b = blockIdx.x;
    const int tid = threadIdx.x;
    const int lane8 = tid & 7;
    const int rgrp = tid >> 3;             // 0..127
    const float* p = pw + (size_t)b * PSTRIDE;

    const f32x4 ka = *(const f32x4*)(p + K_OFF + lane8 * 8);
    const f32x4 kb = *(const f32x4*)(p + K_OFF + lane8 * 8 + 4);
    const float combo = p[COMBO_OFF];
    const float* memb = memory + (size_t)b * RR * CC;

    // ---- phase 0: stream + cosine + exp (4-row batched loads) ----
    float lsum = 0.f;
    #pragma unroll
    for (int mi = 0; mi < 4; ++mi) {
        f32x4 ma[4], mb[4];
        #pragma unroll
        for (int j = 0; j < 4; ++j) {
            int r = (mi * 4 + j) * 128 + rgrp;
            const f32x4* mp = (const f32x4*)(memb + (size_t)r * CC + lane8 * 8);
            ma[j] = mp[0];
            mb[j] = mp[1];
        }
        #pragma unroll
        for (int j = 0; j < 4; ++j) {
            int r = (mi * 4 + j) * 128 + rgrp;
            float num = ma[j].x * ka.x + ma[j].y * ka.y + ma[j].z * ka.z
                      + ma[j].w * ka.w + mb[j].x * kb.x + mb[j].y * kb.y
                      + mb[j].z * kb.z + mb[j].w * kb.w;
            float ssq = ma[j].x * ma[j].x + ma[j].y * ma[j].y
                      + ma[j].z * ma[j].z + ma[j].w * ma[j].w
                      + mb[j].x * mb[j].x + mb[j].y * mb[j].y
                      + mb[j].z * mb[j].z + mb[j].w * mb[j].w;
            #pragma unroll
            for (int m = 1; m < 8; m <<= 1) {
                num += __shfl_xor(num, m, 64);
                ssq += __shfl_xor(ssq, m, 64);
            }
            if (lane8 == 0) {
                float mn = fmaxf(sqrtf(ssq), 1e-8f);
                float ev = __expf(combo * num / mn);
                evs[r] = ev;
                lsum += ev;
            }
        }
    }
    const float se = block_reduce_sum16(lsum, red);   // barrier covers evs

    // ---- phase A: gate -> conv -> pow -> normalize (unchanged) ----
    const float g = p[G_OFF];
    const float gamma = p[GAMMA_OFF];
    const float s0 = p[S_OFF + 0], s1 = p[S_OFF + 1], s2 = p[S_OFF + 2],
                s3 = p[S_OFF + 3], s4 = p[S_OFF + 4], s5 = p[S_OFF + 5],
                s6 = p[S_OFF + 6];
    const float gi = g / se, omg = 1.f - g;

    {
        const int r2 = tid * 2;
        float2 pv = *(const float2*)(prev_w + (size_t)b * RR + r2);
        wg[r2]     = gi * evs[r2]     + omg * pv.x;
        wg[r2 + 1] = gi * evs[r2 + 1] + omg * pv.y;
    }
    __syncthreads();

    float lp = 0.f;
    {
        const int r2 = tid * 2;
        #pragma unroll
        for (int q = 0; q < 2; ++q) {
            int r = r2 + q;
            float acc = s0 * wg[(r - 3) & (RR - 1)]
                      + s1 * wg[(r - 2) & (RR - 1)]
                      + s2 * wg[(r - 1) & (RR - 1)]
                      + s3 * wg[r]
                      + s4 * wg[(r + 1) & (RR - 1)]
                      + s5 * wg[(r + 2) & (RR - 1)]
                      + s6 * wg[(r + 3) & (RR - 1)];
            float v = __powf(acc, gamma);
            evs[r] = v;
            lp += v;
        }
    }
    const float ps = block_reduce_sum16(lp, red);     // barrier: conv reads done
    const float invp = 1.f / (ps + 1e-16f);

    {
        const int r2 = tid * 2;
        float w0 = evs[r2] * invp;
        float w1 = evs[r2 + 1] * invp;
        wg[r2] = w0;
        wg[r2 + 1] = w1;
        *(float2*)(out_w + (size_t)b * RR + r2) = make_float2(w0, w1);
    }
    __syncthreads();

    // ---- phase B: memory update (4-row batched loads, plain stores) ----
    const f32x4 ea = *(const f32x4*)(p + E_OFF + lane8 * 8);
    const f32x4 eb = *(const f32x4*)(p + E_OFF + lane8 * 8 + 4);
    const f32x4 aa = *(const f32x4*)(p + A_OFF + lane8 * 8);
    const f32x4 ab = *(const f32x4*)(p + A_OFF + lane8 * 8 + 4);
    float* omb = out_mem + (size_t)b * RR * CC;

    #pragma unroll
    for (int mi = 0; mi < 4; ++mi) {
        f32x4 ma[4], mb[4];
        float wv[4];
        #pragma unroll
        for (int j = 0; j < 4; ++j) {
            int r = (mi * 4 + j) * 128 + rgrp;
            const f32x4* mp = (const f32x4*)(memb + (size_t)r * CC + lane8 * 8);
            ma[j] = mp[0];
            mb[j] = mp[1];
            wv[j] = wg[r];
        }
        #pragma unroll
        for (int j = 0; j < 4; ++j) {
            int r = (mi * 4 + j) * 128 + rgrp;
            f32x4 oa, ob;
            oa.x = ma[j].x * (1.f - wv[j] * ea.x) + wv[j] * aa.x;
            oa.y = ma[j].y * (1.f - wv[j] * ea.y) + wv[j] * aa.y;
            oa.z = ma[j].z * (1.f - wv[j] * ea.z) + wv[j] * aa.z;
            oa.w = ma[j].w * (1.f - wv[j] * ea.w) + wv[j] * aa.w;
            ob.x = mb[j].x * (1.f - wv[j] * eb.x) + wv[j] * ab.x;
            ob.y = mb[j].y * (1.f - wv[j] * eb.y) + wv[j] * ab.y;
            ob.z = mb[j].z * (1.f - wv[j] * eb.z) + wv[j] * ab.z;
            ob.w = mb[j].w * (1.f - wv[j] * eb.w) + wv[j] * ab.w;
            f32x4* op = (f32x4*)(omb + (size_t)r * CC + lane8 * 8);
            op[0] = oa;
            op[1] = ob;
        }
    }
}

extern "C" void kernel_launch(void* const* d_in, const int* in_sizes, int n_in,
                              void* d_out, int out_size, void* d_ws, size_t ws_size,
                              hipStream_t stream) {
    const float* h      = (const float*)d_in[0];
    const float* prev_w = (const float*)d_in[1];
    const float* memory = (const float*)d_in[2];
    const float* fc_w   = (const float*)d_in[3];
    const float* fc_b   = (const float*)d_in[4];

    float* pw      = (float*)d_ws;              // 512*208*4 = 416 KB
    float* out_w   = (float*)d_out;             // B*R
    float* out_mem = out_w + (size_t)BB * RR;   // B*R*C

    params_kernel<<<64, 256, 0, stream>>>(h, fc_w, fc_b, pw);
    fused_kernel<<<BB, 1024, 0, stream>>>(memory, prev_w, pw, out_w, out_mem);
}